// Round 1
// baseline (53478.168 us; speedup 1.0000x reference)
//
#include <hip/hip_runtime.h>

#define Bn 4096
#define Tn 256
#define NZ 64
#define Hn 512
#define G4n 2048
#define INn 68
#define DPRv 24.0f
#define MB 32
#define NWAVE 8
#define NTHREADS 512
#define NBLK (Bn / MB) /* 128 */

typedef short short8 __attribute__((ext_vector_type(8)));
typedef float floatx16 __attribute__((ext_vector_type(16)));

__device__ __forceinline__ unsigned short f2bf(float f) {
  unsigned int u = __float_as_uint(f);
  u += 0x7FFFu + ((u >> 16) & 1u);
  return (unsigned short)(u >> 16);
}
__device__ __forceinline__ float fsig(float x) {
  return __builtin_amdgcn_rcpf(1.0f + __builtin_amdgcn_exp2f(x * -1.4426950408889634f));
}
__device__ __forceinline__ float ftanh(float x) {
  return 1.0f - 2.0f * __builtin_amdgcn_rcpf(1.0f + __builtin_amdgcn_exp2f(x * 2.8853900817779268f));
}

// Convert weights to bf16 into workspace. Layout:
//   wbhh [2048][512]  (W_hh rows)
//   wb1  [512][512]   (W1 rows)
//   wbext[2048][80]   cols 0..63 = W_ih[:,3..66] (noise), 64=W_ih[:,0], 65=W_ih[:,1],
//                     66 = 0 (dp handled in f32), 67=W_ih[:,67] (clus), 68..79 = 0
__global__ void prep_weights(const float* __restrict__ Wih, const float* __restrict__ Whh,
                             const float* __restrict__ W1u,
                             unsigned short* __restrict__ wbhh, unsigned short* __restrict__ wb1,
                             unsigned short* __restrict__ wbext) {
  int idx = blockIdx.x * blockDim.x + threadIdx.x;
  if (idx < G4n * Hn) wbhh[idx] = f2bf(Whh[idx]);
  if (idx < Hn * Hn) wb1[idx] = f2bf(W1u[idx]);
  if (idx < G4n * 80) {
    int n = idx / 80, j = idx - n * 80;
    float v = 0.0f;
    if (j < 64) v = Wih[n * INn + 3 + j];
    else if (j == 64) v = Wih[n * INn + 0];
    else if (j == 65) v = Wih[n * INn + 1];
    else if (j == 67) v = Wih[n * INn + 67];
    wbext[idx] = f2bf(v);
  }
}

// Persistent recurrent kernel: each block owns 32 batch rows for all 256 steps.
__launch_bounds__(NTHREADS, 2)
__global__ void lstm_seq(const float* __restrict__ noise, const float* __restrict__ cluster,
                         const float* __restrict__ gap, const float* __restrict__ Wih,
                         const float* __restrict__ bih, const float* __restrict__ bhh,
                         const float* __restrict__ b1p, const float* __restrict__ W2p,
                         const float* __restrict__ b2p,
                         const unsigned short* __restrict__ wbhh,
                         const unsigned short* __restrict__ wb1,
                         const unsigned short* __restrict__ wbext,
                         float* __restrict__ out) {
  // h in bf16 A-fragment layout, XOR-swizzled: byte(r,col) = r*1024 + ((col*2) ^ (r<<4))
  __shared__ __align__(16) unsigned short hA[MB * Hn];      // 32 KB
  // extras tile [32 rows][128 cols padded], swizzle: byte = r*256 + ((col*2) ^ ((r&15)<<4))
  __shared__ __align__(16) unsigned short extA[MB * 128];   // 8 KB
  __shared__ float partial[NWAVE][MB];
  __shared__ float dp_lds[MB];

  const int tid = threadIdx.x;
  const int w = tid >> 6;
  const int lane = tid & 63;
  const int l31 = lane & 31;
  const int half = lane >> 5;
  const int r0 = blockIdx.x * MB;
  const int cb = w * 64;           // this wave's hidden-column base
  const int c0 = cb + l31;         // sub-tile 0 column
  const int c1 = cb + 32 + l31;    // sub-tile 1 column

  // ---- zero LDS (h0 = 0; ext padding = 0) ----
  short8 zero8 = {0, 0, 0, 0, 0, 0, 0, 0};
  for (int i = tid; i < MB * Hn / 8; i += NTHREADS) ((short8*)hA)[i] = zero8;
  for (int i = tid; i < MB * 128 / 8; i += NTHREADS) ((short8*)extA)[i] = zero8;

  // ---- loop-invariant preloads ----
  float biasv[4][2], wih2[4][2];
  int offh[4][2], offe[4][2];
#pragma unroll
  for (int g = 0; g < 4; ++g)
#pragma unroll
    for (int s = 0; s < 2; ++s) {
      int n = g * Hn + cb + s * 32 + l31;
      biasv[g][s] = bih[n] + bhh[n];
      wih2[g][s] = Wih[n * INn + 2];   // dp column of W_ih (exact f32 path)
      offh[g][s] = n * Hn;
      offe[g][s] = n * 80;
    }
  const int offz0 = c0 * Hn, offz1 = c1 * Hn;
  const float b1v0 = b1p[c0], b1v1 = b1p[c1];
  const float w2v0 = W2p[c0], w2v1 = W2p[c1];
  const float b2v = b2p[0];
  const float clusf = cluster[r0 + (tid & 31)];

  // ---- stage extras for t = 0 ----
  {
    const int row = tid >> 4, kq = (tid & 15) << 2;
    const float4 v = *(const float4*)(noise + ((size_t)(r0 + row) * Tn + 0) * NZ + kq);
    ushort4 hb;
    hb.x = f2bf(v.x); hb.y = f2bf(v.y); hb.z = f2bf(v.z); hb.w = f2bf(v.w);
    *(ushort4*)((char*)extA + row * 256 + ((kq << 1) ^ ((row & 15) << 4))) = hb;
    if (tid < MB) {
      const size_t gb = ((size_t)(r0 + tid) * (Tn + 1) + 0) * 2;
      ushort4 hg;
      hg.x = f2bf(gap[gb]); hg.y = f2bf(gap[gb + 1]); hg.z = 0; hg.w = f2bf(clusf);
      *(ushort4*)((char*)extA + tid * 256 + (128 ^ ((tid & 15) << 4))) = hg;
    }
  }

  float c_reg0[16], c_reg1[16];
#pragma unroll
  for (int q = 0; q < 16; ++q) { c_reg0[q] = 0.f; c_reg1[q] = 0.f; }

  __syncthreads();

  for (int t = 0; t <= Tn; ++t) {
    // ================= phase Z: z = tanh(h @ W1^T + b1), dp partials =================
    floatx16 zacc[2];
#pragma unroll
    for (int s = 0; s < 2; ++s)
#pragma unroll
      for (int q = 0; q < 16; ++q) zacc[s][q] = 0.f;

    for (int kk = 0; kk < 32; ++kk) {
      const int k0 = (kk << 4) + (half << 3);
      const short8 a = *(const short8*)((const char*)hA + (l31 << 10) + ((k0 << 1) ^ (l31 << 4)));
      zacc[0] = __builtin_amdgcn_mfma_f32_32x32x16_bf16(a, *(const short8*)(wb1 + offz0 + k0), zacc[0], 0, 0, 0);
      zacc[1] = __builtin_amdgcn_mfma_f32_32x32x16_bf16(a, *(const short8*)(wb1 + offz1 + k0), zacc[1], 0, 0, 0);
    }

    float part[16];
#pragma unroll
    for (int q = 0; q < 16; ++q) {
      const float z0 = ftanh(zacc[0][q] + b1v0);
      const float z1 = ftanh(zacc[1][q] + b1v1);
      part[q] = z0 * w2v0 + z1 * w2v1;
    }
#pragma unroll
    for (int m = 1; m <= 16; m <<= 1)
#pragma unroll
      for (int q = 0; q < 16; ++q) part[q] += __shfl_xor(part[q], m, 64);
    if (l31 == 0) {
#pragma unroll
      for (int q = 0; q < 16; ++q)
        partial[w][(q & 3) + ((q >> 2) << 3) + (half << 2)] = part[q];
    }

    // ================= phase G: gates = h @ W_hh^T + ext @ W_ext^T =================
    floatx16 acc[4][2];
#pragma unroll
    for (int g = 0; g < 4; ++g)
#pragma unroll
      for (int s = 0; s < 2; ++s)
#pragma unroll
        for (int q = 0; q < 16; ++q) acc[g][s][q] = 0.f;

    for (int kk = 0; kk < 32; ++kk) {
      const int k0 = (kk << 4) + (half << 3);
      const short8 a = *(const short8*)((const char*)hA + (l31 << 10) + ((k0 << 1) ^ (l31 << 4)));
#pragma unroll
      for (int g = 0; g < 4; ++g)
#pragma unroll
        for (int s = 0; s < 2; ++s)
          acc[g][s] = __builtin_amdgcn_mfma_f32_32x32x16_bf16(
              a, *(const short8*)(wbhh + offh[g][s] + k0), acc[g][s], 0, 0, 0);
    }
#pragma unroll
    for (int kk = 0; kk < 5; ++kk) {
      const int k0 = (kk << 4) + (half << 3);
      const short8 a = *(const short8*)((const char*)extA + (l31 << 8) + ((k0 << 1) ^ ((l31 & 15) << 4)));
#pragma unroll
      for (int g = 0; g < 4; ++g)
#pragma unroll
        for (int s = 0; s < 2; ++s)
          acc[g][s] = __builtin_amdgcn_mfma_f32_32x32x16_bf16(
              a, *(const short8*)(wbext + offe[g][s] + k0), acc[g][s], 0, 0, 0);
    }

    __syncthreads();  // B1: partial complete; all reads of hA/extA complete

    // ================= dp + output + stage extras for t+1 =================
    if (tid < MB) {
      float ssum = b2v;
#pragma unroll
      for (int ww = 0; ww < NWAVE; ++ww) ssum += partial[ww][tid];
      const float dpv = DPRv * ftanh(ssum);
      dp_lds[tid] = dpv;
      const size_t gb = ((size_t)(r0 + tid) * (Tn + 1) + t) * 2;
      const float g0 = gap[gb], g1 = gap[gb + 1];
      float* op = out + ((size_t)(r0 + tid) * (Tn + 1) + t) * 3;
      op[0] = g0; op[1] = g1; op[2] = dpv;
    }
    if (t < Tn - 1) {
      const int row = tid >> 4, kq = (tid & 15) << 2;
      const float4 v = *(const float4*)(noise + ((size_t)(r0 + row) * Tn + (t + 1)) * NZ + kq);
      ushort4 hb;
      hb.x = f2bf(v.x); hb.y = f2bf(v.y); hb.z = f2bf(v.z); hb.w = f2bf(v.w);
      *(ushort4*)((char*)extA + row * 256 + ((kq << 1) ^ ((row & 15) << 4))) = hb;
      if (tid < MB) {
        const size_t gb = ((size_t)(r0 + tid) * (Tn + 1) + (t + 1)) * 2;
        ushort4 hg;
        hg.x = f2bf(gap[gb]); hg.y = f2bf(gap[gb + 1]); hg.z = 0; hg.w = f2bf(clusf);
        *(ushort4*)((char*)extA + tid * 256 + (128 ^ ((tid & 15) << 4))) = hg;
      }
    }
    __syncthreads();  // B2: dp_lds visible; hA safe to overwrite

    // ================= cell update, write h (bf16, swizzled) =================
    if (t < Tn) {
      float dpv[16];
#pragma unroll
      for (int q = 0; q < 16; ++q)
        dpv[q] = dp_lds[(q & 3) + ((q >> 2) << 3) + (half << 2)];
#pragma unroll
      for (int s = 0; s < 2; ++s) {
        const int colb = (cb + s * 32 + l31) << 1;
#pragma unroll
        for (int q = 0; q < 16; ++q) {
          const float gi = acc[0][s][q] + biasv[0][s] + dpv[q] * wih2[0][s];
          const float gf = acc[1][s][q] + biasv[1][s] + dpv[q] * wih2[1][s];
          const float gg = acc[2][s][q] + biasv[2][s] + dpv[q] * wih2[2][s];
          const float go = acc[3][s][q] + biasv[3][s] + dpv[q] * wih2[3][s];
          float cv = (s == 0) ? c_reg0[q] : c_reg1[q];
          cv = fsig(gf) * cv + fsig(gi) * ftanh(gg);
          const float hv = fsig(go) * ftanh(cv);
          if (s == 0) c_reg0[q] = cv; else c_reg1[q] = cv;
          const int r = (q & 3) + ((q >> 2) << 3) + (half << 2);
          *(unsigned short*)((char*)hA + (r << 10) + (colb ^ (r << 4))) = f2bf(hv);
        }
      }
    }
    __syncthreads();  // B3: hA ready for next step
  }
}

extern "C" void kernel_launch(void* const* d_in, const int* in_sizes, int n_in,
                              void* d_out, int out_size, void* d_ws, size_t ws_size,
                              hipStream_t stream) {
  const float* noise   = (const float*)d_in[0];
  const float* cluster = (const float*)d_in[1];
  const float* gap     = (const float*)d_in[2];
  const float* Wih     = (const float*)d_in[3];
  const float* Whh     = (const float*)d_in[4];
  const float* bih     = (const float*)d_in[5];
  const float* bhh     = (const float*)d_in[6];
  const float* W1      = (const float*)d_in[7];
  const float* b1      = (const float*)d_in[8];
  const float* W2      = (const float*)d_in[9];
  const float* b2      = (const float*)d_in[10];

  unsigned short* wbhh  = (unsigned short*)d_ws;
  unsigned short* wb1   = wbhh + (size_t)G4n * Hn;
  unsigned short* wbext = wb1 + (size_t)Hn * Hn;

  prep_weights<<<(G4n * Hn) / 256, 256, 0, stream>>>(Wih, Whh, W1, wbhh, wb1, wbext);
  lstm_seq<<<NBLK, NTHREADS, 0, stream>>>(noise, cluster, gap, Wih, bih, bhh, b1, W2, b2,
                                          wbhh, wb1, wbext, (float*)d_out);
}

// Round 2
// 53254.486 us; speedup vs baseline: 1.0042x; 1.0042x over previous
//
#include <hip/hip_runtime.h>

#define Bn 4096
#define Tn 256
#define NZ 64
#define Hn 512
#define G4n 2048
#define INn 68
#define DPRv 24.0f
#define MB 32
#define NWAVE 8
#define NTHREADS 512
#define NBLK (Bn / MB) /* 128 */

// packed stream geometry (unsigned short units)
#define PK_WSTRIDE (32 * 10 * 64 * 8) /* 163840 per wave */
#define PK_KSTRIDE (10 * 64 * 8)      /* 5120 per kk */
#define PK_FSTRIDE (64 * 8)           /* 512 per fragment */
#define EP_WSTRIDE (5 * 8 * 64 * 8)   /* 20480 per wave */
#define EP_KSTRIDE (8 * 64 * 8)       /* 4096 per kk */

typedef short short8 __attribute__((ext_vector_type(8)));
typedef float floatx16 __attribute__((ext_vector_type(16)));

__device__ __forceinline__ unsigned short f2bf(float f) {
  unsigned int u = __float_as_uint(f);
  u += 0x7FFFu + ((u >> 16) & 1u);
  return (unsigned short)(u >> 16);
}
__device__ __forceinline__ float fsig(float x) {
  return __builtin_amdgcn_rcpf(1.0f + __builtin_amdgcn_exp2f(x * -1.4426950408889634f));
}
__device__ __forceinline__ float ftanh(float x) {
  return 1.0f - 2.0f * __builtin_amdgcn_rcpf(1.0f + __builtin_amdgcn_exp2f(x * 2.8853900817779268f));
}

// Pack weights (bf16) in the exact per-(wave,kk,fragment,lane) consumption order.
// pk fragment f at (w,kk): f=0,1 -> W1 rows w*64 + f*32 + l31 (z phase);
//                          f=2..9 -> g=(f-2)>>1, s=(f-2)&1, W_hh row g*512+w*64+s*32+l31.
// Each fragment element j = source col k0+j, k0 = kk*16 + half*8.
// epk: ext weights (W_ih rearranged cols: [noise 0..63][gap0][gap1][dp=0][clus][pad..79]).
__global__ void prep_pack(const float* __restrict__ Wih, const float* __restrict__ Whh,
                          const float* __restrict__ W1u,
                          unsigned short* __restrict__ pk, unsigned short* __restrict__ epk) {
  const int idx = blockIdx.x * blockDim.x + threadIdx.x;
  if (idx < 163840) {
    const int lane = idx & 63;
    const int fragid = idx >> 6;
    const int f = fragid % 10;
    const int kk = (fragid / 10) % 32;
    const int w = fragid / 320;
    const int l31 = lane & 31, half = lane >> 5;
    const int k0 = kk * 16 + half * 8;
    unsigned short* dst = pk + (size_t)idx * 8;
    if (f < 2) {
      const int n = w * 64 + f * 32 + l31;
#pragma unroll
      for (int j = 0; j < 8; ++j) dst[j] = f2bf(W1u[n * Hn + k0 + j]);
    } else {
      const int g = (f - 2) >> 1, s = (f - 2) & 1;
      const int n = g * Hn + w * 64 + s * 32 + l31;
#pragma unroll
      for (int j = 0; j < 8; ++j) dst[j] = f2bf(Whh[n * Hn + k0 + j]);
    }
  }
  const int e = idx - 163840;
  if (e >= 0 && e < 20480) {
    const int lane = e & 63;
    const int fragid = e >> 6;
    const int fs = fragid % 8;
    const int kk = (fragid / 8) % 5;
    const int w = fragid / 40;
    const int g = fs >> 1, s = fs & 1;
    const int l31 = lane & 31, half = lane >> 5;
    const int n = g * Hn + w * 64 + s * 32 + l31;
    unsigned short* dst = epk + (size_t)e * 8;
#pragma unroll
    for (int j = 0; j < 8; ++j) {
      const int c = kk * 16 + half * 8 + j;
      float v = 0.0f;
      if (c < 64) v = Wih[n * INn + 3 + c];
      else if (c == 64) v = Wih[n * INn + 0];
      else if (c == 65) v = Wih[n * INn + 1];
      else if (c == 67) v = Wih[n * INn + 67];
      dst[j] = f2bf(v);
    }
  }
}

// Persistent recurrent kernel: each block owns 32 batch rows for all 256 steps.
__launch_bounds__(NTHREADS, 2)
__global__ void lstm_seq(const float* __restrict__ noise, const float* __restrict__ cluster,
                         const float* __restrict__ gap, const float* __restrict__ Wih,
                         const float* __restrict__ bih, const float* __restrict__ bhh,
                         const float* __restrict__ b1p, const float* __restrict__ W2p,
                         const float* __restrict__ b2p,
                         const unsigned short* __restrict__ pk,
                         const unsigned short* __restrict__ epk,
                         float* __restrict__ out) {
  // h in bf16 A-fragment layout, XOR-swizzled: byte(r,col) = r*1024 + ((col*2) ^ (r<<4))
  __shared__ __align__(16) unsigned short hA[MB * Hn];      // 32 KB
  // extras tile [32 rows][128 cols padded], swizzle: byte = r*256 + ((col*2) ^ ((r&15)<<4))
  __shared__ __align__(16) unsigned short extA[MB * 128];   // 8 KB
  __shared__ float partial[NWAVE][MB];
  __shared__ float dp_lds[MB];

  const int tid = threadIdx.x;
  const int w = tid >> 6;
  const int lane = tid & 63;
  const int l31 = lane & 31;
  const int half = lane >> 5;
  const int r0 = blockIdx.x * MB;
  const int cb = w * 64;           // this wave's hidden-column base
  const int c0 = cb + l31;         // sub-tile 0 column
  const int c1 = cb + 32 + l31;    // sub-tile 1 column

  // ---- zero LDS (h0 = 0; ext padding = 0) ----
  short8 zero8 = {0, 0, 0, 0, 0, 0, 0, 0};
  for (int i = tid; i < MB * Hn / 8; i += NTHREADS) ((short8*)hA)[i] = zero8;
  for (int i = tid; i < MB * 128 / 8; i += NTHREADS) ((short8*)extA)[i] = zero8;

  // ---- loop-invariant preloads ----
  float biasv[4][2], wih2[4][2];
#pragma unroll
  for (int g = 0; g < 4; ++g)
#pragma unroll
    for (int s = 0; s < 2; ++s) {
      int n = g * Hn + cb + s * 32 + l31;
      biasv[g][s] = bih[n] + bhh[n];
      wih2[g][s] = Wih[n * INn + 2];   // dp column of W_ih (exact f32 path)
    }
  const float b1v0 = b1p[c0], b1v1 = b1p[c1];
  const float w2v0 = W2p[c0], w2v1 = W2p[c1];
  const float b2v = b2p[0];
  const float clusf = cluster[r0 + (tid & 31)];

  const unsigned short* const ps = pk + (size_t)w * PK_WSTRIDE + (size_t)lane * 8;
  const unsigned short* const es = epk + (size_t)w * EP_WSTRIDE + (size_t)lane * 8;

  // ---- stage extras for t = 0 ----
  {
    const int row = tid >> 4, kq = (tid & 15) << 2;
    const float4 v = *(const float4*)(noise + ((size_t)(r0 + row) * Tn + 0) * NZ + kq);
    ushort4 hb;
    hb.x = f2bf(v.x); hb.y = f2bf(v.y); hb.z = f2bf(v.z); hb.w = f2bf(v.w);
    *(ushort4*)((char*)extA + row * 256 + ((kq << 1) ^ ((row & 15) << 4))) = hb;
    if (tid < MB) {
      const size_t gb = ((size_t)(r0 + tid) * (Tn + 1) + 0) * 2;
      ushort4 hg;
      hg.x = f2bf(gap[gb]); hg.y = f2bf(gap[gb + 1]); hg.z = 0; hg.w = f2bf(clusf);
      *(ushort4*)((char*)extA + tid * 256 + (128 ^ ((tid & 15) << 4))) = hg;
    }
  }

  float c_reg0[16], c_reg1[16];
#pragma unroll
  for (int q = 0; q < 16; ++q) { c_reg0[q] = 0.f; c_reg1[q] = 0.f; }

  __syncthreads();

  for (int t = 0; t <= Tn; ++t) {
    // ========== fused Z + G phase: one sequential 320KB weight stream per wave ==========
    floatx16 zacc[2];
    floatx16 acc[4][2];
#pragma unroll
    for (int s = 0; s < 2; ++s)
#pragma unroll
      for (int q = 0; q < 16; ++q) zacc[s][q] = 0.f;
#pragma unroll
    for (int g = 0; g < 4; ++g)
#pragma unroll
      for (int s = 0; s < 2; ++s)
#pragma unroll
        for (int q = 0; q < 16; ++q) acc[g][s][q] = 0.f;

    for (int kk = 0; kk < 32; ++kk) {
      const int k0 = (kk << 4) + (half << 3);
      const short8 a = *(const short8*)((const char*)hA + (l31 << 10) + ((k0 << 1) ^ (l31 << 4)));
      const unsigned short* pb = ps + kk * PK_KSTRIDE;
      zacc[0] = __builtin_amdgcn_mfma_f32_32x32x16_bf16(a, *(const short8*)(pb), zacc[0], 0, 0, 0);
      zacc[1] = __builtin_amdgcn_mfma_f32_32x32x16_bf16(a, *(const short8*)(pb + PK_FSTRIDE), zacc[1], 0, 0, 0);
#pragma unroll
      for (int g = 0; g < 4; ++g)
#pragma unroll
        for (int s = 0; s < 2; ++s)
          acc[g][s] = __builtin_amdgcn_mfma_f32_32x32x16_bf16(
              a, *(const short8*)(pb + (2 + g * 2 + s) * PK_FSTRIDE), acc[g][s], 0, 0, 0);
    }
#pragma unroll
    for (int kk = 0; kk < 5; ++kk) {
      const int k0 = (kk << 4) + (half << 3);
      const short8 a = *(const short8*)((const char*)extA + (l31 << 8) + ((k0 << 1) ^ ((l31 & 15) << 4)));
      const unsigned short* eb = es + kk * EP_KSTRIDE;
#pragma unroll
      for (int g = 0; g < 4; ++g)
#pragma unroll
        for (int s = 0; s < 2; ++s)
          acc[g][s] = __builtin_amdgcn_mfma_f32_32x32x16_bf16(
              a, *(const short8*)(eb + (g * 2 + s) * PK_FSTRIDE), acc[g][s], 0, 0, 0);
    }

    // z finish + dp partials
    {
      float part[16];
#pragma unroll
      for (int q = 0; q < 16; ++q) {
        const float z0 = ftanh(zacc[0][q] + b1v0);
        const float z1 = ftanh(zacc[1][q] + b1v1);
        part[q] = z0 * w2v0 + z1 * w2v1;
      }
#pragma unroll
      for (int m = 1; m <= 16; m <<= 1)
#pragma unroll
        for (int q = 0; q < 16; ++q) part[q] += __shfl_xor(part[q], m, 64);
      if (l31 == 0) {
#pragma unroll
        for (int q = 0; q < 16; ++q)
          partial[w][(q & 3) + ((q >> 2) << 3) + (half << 2)] = part[q];
      }
    }

    __syncthreads();  // B1: partial complete; all reads of hA/extA complete

    // ================= dp + output + stage extras for t+1 =================
    if (tid < MB) {
      float ssum = b2v;
#pragma unroll
      for (int ww = 0; ww < NWAVE; ++ww) ssum += partial[ww][tid];
      const float dpv = DPRv * ftanh(ssum);
      dp_lds[tid] = dpv;
      const size_t gb = ((size_t)(r0 + tid) * (Tn + 1) + t) * 2;
      const float g0 = gap[gb], g1 = gap[gb + 1];
      float* op = out + ((size_t)(r0 + tid) * (Tn + 1) + t) * 3;
      op[0] = g0; op[1] = g1; op[2] = dpv;
    }
    if (t < Tn - 1) {
      const int row = tid >> 4, kq = (tid & 15) << 2;
      const float4 v = *(const float4*)(noise + ((size_t)(r0 + row) * Tn + (t + 1)) * NZ + kq);
      ushort4 hb;
      hb.x = f2bf(v.x); hb.y = f2bf(v.y); hb.z = f2bf(v.z); hb.w = f2bf(v.w);
      *(ushort4*)((char*)extA + row * 256 + ((kq << 1) ^ ((row & 15) << 4))) = hb;
      if (tid < MB) {
        const size_t gb = ((size_t)(r0 + tid) * (Tn + 1) + (t + 1)) * 2;
        ushort4 hg;
        hg.x = f2bf(gap[gb]); hg.y = f2bf(gap[gb + 1]); hg.z = 0; hg.w = f2bf(clusf);
        *(ushort4*)((char*)extA + tid * 256 + (128 ^ ((tid & 15) << 4))) = hg;
      }
    }
    __syncthreads();  // B2: dp_lds visible; hA safe to overwrite

    // ================= cell update, write h (bf16, swizzled) =================
    if (t < Tn) {
      float dpv[16];
#pragma unroll
      for (int q = 0; q < 16; ++q)
        dpv[q] = dp_lds[(q & 3) + ((q >> 2) << 3) + (half << 2)];
#pragma unroll
      for (int s = 0; s < 2; ++s) {
        const int colb = (cb + s * 32 + l31) << 1;
#pragma unroll
        for (int q = 0; q < 16; ++q) {
          const float gi = acc[0][s][q] + biasv[0][s] + dpv[q] * wih2[0][s];
          const float gf = acc[1][s][q] + biasv[1][s] + dpv[q] * wih2[1][s];
          const float gg = acc[2][s][q] + biasv[2][s] + dpv[q] * wih2[2][s];
          const float go = acc[3][s][q] + biasv[3][s] + dpv[q] * wih2[3][s];
          float cv = (s == 0) ? c_reg0[q] : c_reg1[q];
          cv = fsig(gf) * cv + fsig(gi) * ftanh(gg);
          const float hv = fsig(go) * ftanh(cv);
          if (s == 0) c_reg0[q] = cv; else c_reg1[q] = cv;
          const int r = (q & 3) + ((q >> 2) << 3) + (half << 2);
          *(unsigned short*)((char*)hA + (r << 10) + (colb ^ (r << 4))) = f2bf(hv);
        }
      }
    }
    __syncthreads();  // B3: hA ready for next step
  }
}

extern "C" void kernel_launch(void* const* d_in, const int* in_sizes, int n_in,
                              void* d_out, int out_size, void* d_ws, size_t ws_size,
                              hipStream_t stream) {
  const float* noise   = (const float*)d_in[0];
  const float* cluster = (const float*)d_in[1];
  const float* gap     = (const float*)d_in[2];
  const float* Wih     = (const float*)d_in[3];
  const float* Whh     = (const float*)d_in[4];
  const float* bih     = (const float*)d_in[5];
  const float* bhh     = (const float*)d_in[6];
  const float* W1      = (const float*)d_in[7];
  const float* b1      = (const float*)d_in[8];
  const float* W2      = (const float*)d_in[9];
  const float* b2      = (const float*)d_in[10];

  unsigned short* pkw = (unsigned short*)d_ws;                    // 8*163840 shorts = 2.5 MB
  unsigned short* epk = pkw + (size_t)NWAVE * PK_WSTRIDE;         // 8*20480 shorts = 320 KB

  prep_pack<<<(184320 + 255) / 256, 256, 0, stream>>>(Wih, Whh, W1, pkw, epk);
  lstm_seq<<<NBLK, NTHREADS, 0, stream>>>(noise, cluster, gap, Wih, bih, bhh, b1, W2, b2,
                                          pkw, epk, (float*)d_out);
}